// Round 4
// baseline (180.643 us; speedup 1.0000x reference)
//
#include <hip/hip_runtime.h>
#include <stdint.h>
#include <stddef.h>

typedef __attribute__((ext_vector_type(4))) int i32x4;

#define AS1q __attribute__((address_space(1)))
#define AS3q __attribute__((address_space(3)))

__device__ __forceinline__ void gload16(const void* g, void* l) {
    __builtin_amdgcn_global_load_lds((const AS1q uint32_t*)g, (AS3q uint32_t*)l, 16, 0, 0);
}

#define VMCNT(n)  asm volatile("s_waitcnt vmcnt(" #n ")" ::: "memory")
#define BARRIER() asm volatile("s_barrier" ::: "memory")

#define EPSQ 1e-8f

// ---------------- Quant: one block per token (K == 4096 fast path) ----------------
__global__ __launch_bounds__(256) void quant4096(
    const float* __restrict__ x, int8_t* __restrict__ xq, float* __restrict__ sx)
{
    constexpr int K = 4096;
    const int t = blockIdx.x;
    const int tid = threadIdx.x;
    const float4* row4 = (const float4*)(x + (size_t)t * K);
    float4 v0 = row4[0 * 256 + tid];
    float4 v1 = row4[1 * 256 + tid];
    float4 v2 = row4[2 * 256 + tid];
    float4 v3 = row4[3 * 256 + tid];
    auto mx4 = [](float4 a) {
        return fmaxf(fmaxf(fabsf(a.x), fabsf(a.y)), fmaxf(fabsf(a.z), fabsf(a.w)));
    };
    float am = fmaxf(fmaxf(mx4(v0), mx4(v1)), fmaxf(mx4(v2), mx4(v3)));
    #pragma unroll
    for (int off = 32; off > 0; off >>= 1)
        am = fmaxf(am, __shfl_xor(am, off, 64));
    __shared__ float wmax[4];
    if ((tid & 63) == 0) wmax[tid >> 6] = am;
    __syncthreads();
    float r = fmaxf(fmaxf(wmax[0], wmax[1]), fmaxf(wmax[2], wmax[3]));
    const float s = fmaxf(r, EPSQ) / 127.0f;   // true fdiv: match reference
    if (tid == 0) sx[t] = s;
    int* qrow = (int*)(xq + (size_t)t * K);
    auto pack = [&](float4 a) {
        int q0 = (int)fminf(fmaxf(rintf(a.x / s), -128.f), 127.f);
        int q1 = (int)fminf(fmaxf(rintf(a.y / s), -128.f), 127.f);
        int q2 = (int)fminf(fmaxf(rintf(a.z / s), -128.f), 127.f);
        int q3 = (int)fminf(fmaxf(rintf(a.w / s), -128.f), 127.f);
        return (q0 & 255) | ((q1 & 255) << 8) | ((q2 & 255) << 16) | ((q3 & 255) << 24);
    };
    qrow[0 * 256 + tid] = pack(v0);
    qrow[1 * 256 + tid] = pack(v1);
    qrow[2 * 256 + tid] = pack(v2);
    qrow[3 * 256 + tid] = pack(v3);
}

// generic fallback (any K multiple of 4)
__global__ __launch_bounds__(256) void quant_any(
    const float* __restrict__ x, int8_t* __restrict__ xq, float* __restrict__ sx, int K)
{
    const int t = blockIdx.x;
    const int tid = threadIdx.x;
    const float* row = x + (size_t)t * K;
    float am = 0.f;
    for (int i = tid; i < K; i += 256) am = fmaxf(am, fabsf(row[i]));
    #pragma unroll
    for (int off = 32; off > 0; off >>= 1)
        am = fmaxf(am, __shfl_xor(am, off, 64));
    __shared__ float wmax[4];
    if ((tid & 63) == 0) wmax[tid >> 6] = am;
    __syncthreads();
    float r = fmaxf(fmaxf(wmax[0], wmax[1]), fmaxf(wmax[2], wmax[3]));
    const float s = fmaxf(r, EPSQ) / 127.0f;
    if (tid == 0) sx[t] = s;
    int8_t* qrow = xq + (size_t)t * K;
    for (int i = tid; i < K; i += 256) {
        float q = fminf(fmaxf(rintf(row[i] / s), -128.f), 127.f);
        qrow[i] = (int8_t)(int)q;
    }
}

// ---------------- Pack: weight arrives as int32 (harness ABI), repack to int8 ----------------
__global__ __launch_bounds__(256) void pack_w(
    const int* __restrict__ w32, int8_t* __restrict__ w8, long long n4)
{
    const long long stride = (long long)gridDim.x * 256;
    for (long long i = (long long)blockIdx.x * 256 + threadIdx.x; i < n4; i += stride) {
        int4 v = ((const int4*)w32)[i];
        ((int*)w8)[i] = (v.x & 255) | ((v.y & 255) << 8) | ((v.z & 255) << 16) | ((v.w & 255) << 24);
    }
}

// ---------------- int8 GEMM: C[M,N] = xq[M,K] * w[N,K]^T, fused dequant ----------------
// 128x128 tile, BK=64 bytes, 4 waves (2x2), wave tile 64x64 = 4x4 frags of 16x16x64.
// LDS: two 64B logical rows packed per 128B physical row, XOR swizzle x ^= (R&7)<<4
//      (counter-verified conflict-free: SQ_LDS_BANK_CONFLICT == 0).
// Pipeline (T3+T4): 3 LDS buffers, stage 2 tiles ahead; per-iter counted
// s_waitcnt vmcnt(4) + raw s_barrier — never drain to 0 in the main loop.
// Ledger: prologue stages T0,T1 (8 loads out). Iter kt: vmcnt(4) waits T_kt's 4
// (issued 2 iters ago, ~800cyc cover) keeping T_{kt+1}'s 4 in flight; barrier
// (all waves done reading T_{kt-1} -> its buffer reusable); stage T_{kt+2}.
__global__ __launch_bounds__(256) void gemm_i8(
    const int8_t* __restrict__ xq, const int8_t* __restrict__ w,
    const float* __restrict__ sx, const float* __restrict__ scale,
    const float* __restrict__ bias, float* __restrict__ out,
    int M, int N, int K)
{
    __shared__ uint8_t lds[3][2][128 * 64];   // [buf][A/B][8KB] = 48KB
    const int tid  = threadIdx.x;
    const int lane = tid & 63;
    const int wv   = tid >> 6;
    const int wr   = wv >> 1, wc = wv & 1;

    // bijective XCD swizzle (m204)
    const int nwg = gridDim.x;
    const int q8 = nwg >> 3, r8 = nwg & 7;
    const int xcd = blockIdx.x & 7, idx8 = blockIdx.x >> 3;
    const int wg = (xcd < r8 ? xcd * (q8 + 1) : r8 * (q8 + 1) + (xcd - r8) * q8) + idx8;

    const int NBM = M >> 7;
    const int bm = wg % NBM;
    const int bn = wg / NBM;        // col-panel-major: B panel stays L2-resident per XCD
    const int brow = bm << 7, bcol = bn << 7;

    // staging source coords: linear LDS chunk li covers bytes li*16..+15
    int rS[2], cS[2];
    #pragma unroll
    for (int e = 0; e < 2; ++e) {
        int li = e * 256 + tid;
        int R  = li >> 3;                        // 128B physical row
        int xx = ((li & 7) << 4) ^ ((R & 7) << 4);
        rS[e]  = (R << 1) | (xx >> 6);
        cS[e]  = xx & 63;
    }
    const int8_t* sA0 = xq + (size_t)(brow + rS[0]) * K + cS[0];
    const int8_t* sA1 = xq + (size_t)(brow + rS[1]) * K + cS[1];
    const int8_t* sB0 = w  + (size_t)(bcol + rS[0]) * K + cS[0];
    const int8_t* sB1 = w  + (size_t)(bcol + rS[1]) * K + cS[1];

    // fragment LDS byte offsets (lane-dependent, constant over K loop)
    int offA[4], offB[4];
    #pragma unroll
    for (int m = 0; m < 4; ++m) {
        const int c = (lane >> 4) << 4;          // 16B k-chunk per lane quarter
        int r  = wr * 64 + m * 16 + (lane & 15);
        int R  = r >> 1;
        int xx = (((r & 1) << 6) | c) ^ ((R & 7) << 4);
        offA[m] = (R << 7) | xx;
        int rb = wc * 64 + m * 16 + (lane & 15);
        int Rb = rb >> 1;
        int xb = (((rb & 1) << 6) | c) ^ ((Rb & 7) << 4);
        offB[m] = (Rb << 7) | xb;
    }

    i32x4 acc[4][4] = {};

    auto stage = [&](int buf, int kt) {
        const size_t ko = (size_t)kt << 6;
        gload16(sA0 + ko, &lds[buf][0][wv * 1024]);
        gload16(sA1 + ko, &lds[buf][0][4096 + wv * 1024]);
        gload16(sB0 + ko, &lds[buf][1][wv * 1024]);
        gload16(sB1 + ko, &lds[buf][1][4096 + wv * 1024]);
    };

    const int NT = K >> 6;      // 64
    stage(0, 0);
    if (NT > 1) stage(1, 1);
    int cur = 0;
    for (int kt = 0; kt < NT; ++kt) {
        if (kt < NT - 1) { VMCNT(4); } else { VMCNT(0); }   // counted wait: T_kt ready, next stays in flight
        BARRIER();                                          // buf[cur] ready; buf[(cur+2)%3] free
        if (kt + 2 < NT) {
            int nb = cur + 2; if (nb >= 3) nb -= 3;
            stage(nb, kt + 2);
        }
        const uint8_t* At = &lds[cur][0][0];
        const uint8_t* Bt = &lds[cur][1][0];
        i32x4 av[4], bv[4];
        #pragma unroll
        for (int m = 0; m < 4; ++m) av[m] = *(const i32x4*)(At + offA[m]);
        #pragma unroll
        for (int n = 0; n < 4; ++n) bv[n] = *(const i32x4*)(Bt + offB[n]);
        __builtin_amdgcn_s_setprio(1);
        #pragma unroll
        for (int m = 0; m < 4; ++m)
            #pragma unroll
            for (int n = 0; n < 4; ++n)
                acc[m][n] = __builtin_amdgcn_mfma_i32_16x16x64_i8(av[m], bv[n], acc[m][n], 0, 0, 0);
        __builtin_amdgcn_s_setprio(0);
        if (++cur >= 3) cur = 0;
    }

    // epilogue: out = acc * sx[row] * scale[col] + bias[col]
    const int orow = brow + wr * 64;
    const int ocol = bcol + wc * 64;
    float sxv[4][4];
    #pragma unroll
    for (int m = 0; m < 4; ++m)
        #pragma unroll
        for (int j = 0; j < 4; ++j)
            sxv[m][j] = sx[orow + m * 16 + ((lane >> 4) << 2) + j];
    #pragma unroll
    for (int n = 0; n < 4; ++n) {
        const int col = ocol + n * 16 + (lane & 15);
        const float sc = scale[col];
        const float bi = bias[col];
        #pragma unroll
        for (int m = 0; m < 4; ++m) {
            const int rb = orow + m * 16 + ((lane >> 4) << 2);
            #pragma unroll
            for (int j = 0; j < 4; ++j)
                out[(size_t)(rb + j) * N + col] = (float)acc[m][n][j] * sxv[m][j] * sc + bi;
        }
    }
}

extern "C" void kernel_launch(void* const* d_in, const int* in_sizes, int n_in,
                              void* d_out, int out_size, void* d_ws, size_t ws_size,
                              hipStream_t stream) {
    const float* x     = (const float*)d_in[0];
    const int*   w32   = (const int*)d_in[1];     // int8 weight arrives as int32 (harness ABI)
    const float* scale = (const float*)d_in[2];
    const float* bias  = (const float*)d_in[3];
    float* out = (float*)d_out;

    const int N = in_sizes[2];           // 6144
    const int K = in_sizes[1] / N;       // 4096
    const int M = in_sizes[0] / K;       // 4096

    // ws layout: xq [M*K int8] | wq [N*K int8] | sx [M f32]
    int8_t* xqbuf = (int8_t*)d_ws;
    int8_t* wqbuf = (int8_t*)d_ws + (size_t)M * K;
    float*  sxbuf = (float*)((uint8_t*)d_ws + (size_t)M * K + (size_t)N * K);

    if (K == 4096)
        quant4096<<<M, 256, 0, stream>>>(x, xqbuf, sxbuf);
    else
        quant_any<<<M, 256, 0, stream>>>(x, xqbuf, sxbuf, K);

    pack_w<<<2048, 256, 0, stream>>>(w32, wqbuf, (long long)N * K / 4);

    const int nwg = (M / 128) * (N / 128);
    gemm_i8<<<nwg, 256, 0, stream>>>(xqbuf, wqbuf, sxbuf, scale, bias, out, M, N, K);
}

// Round 5
// 160.411 us; speedup vs baseline: 1.1261x; 1.1261x over previous
//
#include <hip/hip_runtime.h>
#include <stdint.h>
#include <stddef.h>

typedef __attribute__((ext_vector_type(4))) int i32x4;

#define AS1q __attribute__((address_space(1)))
#define AS3q __attribute__((address_space(3)))

__device__ __forceinline__ void gload16(const void* g, void* l) {
    __builtin_amdgcn_global_load_lds((const AS1q uint32_t*)g, (AS3q uint32_t*)l, 16, 0, 0);
}

#define VMCNT(n)  asm volatile("s_waitcnt vmcnt(" #n ")" ::: "memory")
#define BARRIER() asm volatile("s_barrier" ::: "memory")

#define EPSQ 1e-8f

// ---------------- Quant: one block per token (K == 4096 fast path) ----------------
__global__ __launch_bounds__(256) void quant4096(
    const float* __restrict__ x, int8_t* __restrict__ xq, float* __restrict__ sx)
{
    constexpr int K = 4096;
    const int t = blockIdx.x;
    const int tid = threadIdx.x;
    const float4* row4 = (const float4*)(x + (size_t)t * K);
    float4 v0 = row4[0 * 256 + tid];
    float4 v1 = row4[1 * 256 + tid];
    float4 v2 = row4[2 * 256 + tid];
    float4 v3 = row4[3 * 256 + tid];
    auto mx4 = [](float4 a) {
        return fmaxf(fmaxf(fabsf(a.x), fabsf(a.y)), fmaxf(fabsf(a.z), fabsf(a.w)));
    };
    float am = fmaxf(fmaxf(mx4(v0), mx4(v1)), fmaxf(mx4(v2), mx4(v3)));
    #pragma unroll
    for (int off = 32; off > 0; off >>= 1)
        am = fmaxf(am, __shfl_xor(am, off, 64));
    __shared__ float wmax[4];
    if ((tid & 63) == 0) wmax[tid >> 6] = am;
    __syncthreads();
    float r = fmaxf(fmaxf(wmax[0], wmax[1]), fmaxf(wmax[2], wmax[3]));
    const float s = fmaxf(r, EPSQ) / 127.0f;   // true fdiv: match reference
    if (tid == 0) sx[t] = s;
    int* qrow = (int*)(xq + (size_t)t * K);
    auto pack = [&](float4 a) {
        int q0 = (int)fminf(fmaxf(rintf(a.x / s), -128.f), 127.f);
        int q1 = (int)fminf(fmaxf(rintf(a.y / s), -128.f), 127.f);
        int q2 = (int)fminf(fmaxf(rintf(a.z / s), -128.f), 127.f);
        int q3 = (int)fminf(fmaxf(rintf(a.w / s), -128.f), 127.f);
        return (q0 & 255) | ((q1 & 255) << 8) | ((q2 & 255) << 16) | ((q3 & 255) << 24);
    };
    qrow[0 * 256 + tid] = pack(v0);
    qrow[1 * 256 + tid] = pack(v1);
    qrow[2 * 256 + tid] = pack(v2);
    qrow[3 * 256 + tid] = pack(v3);
}

// generic fallback (any K multiple of 4)
__global__ __launch_bounds__(256) void quant_any(
    const float* __restrict__ x, int8_t* __restrict__ xq, float* __restrict__ sx, int K)
{
    const int t = blockIdx.x;
    const int tid = threadIdx.x;
    const float* row = x + (size_t)t * K;
    float am = 0.f;
    for (int i = tid; i < K; i += 256) am = fmaxf(am, fabsf(row[i]));
    #pragma unroll
    for (int off = 32; off > 0; off >>= 1)
        am = fmaxf(am, __shfl_xor(am, off, 64));
    __shared__ float wmax[4];
    if ((tid & 63) == 0) wmax[tid >> 6] = am;
    __syncthreads();
    float r = fmaxf(fmaxf(wmax[0], wmax[1]), fmaxf(wmax[2], wmax[3]));
    const float s = fmaxf(r, EPSQ) / 127.0f;
    if (tid == 0) sx[t] = s;
    int8_t* qrow = xq + (size_t)t * K;
    for (int i = tid; i < K; i += 256) {
        float q = fminf(fmaxf(rintf(row[i] / s), -128.f), 127.f);
        qrow[i] = (int8_t)(int)q;
    }
}

// ---------------- Pack: weight arrives as int32 (harness ABI), repack to int8 ----------------
__global__ __launch_bounds__(256) void pack_w(
    const int* __restrict__ w32, int8_t* __restrict__ w8, long long n4)
{
    const long long stride = (long long)gridDim.x * 256;
    for (long long i = (long long)blockIdx.x * 256 + threadIdx.x; i < n4; i += stride) {
        int4 v = ((const int4*)w32)[i];
        ((int*)w8)[i] = (v.x & 255) | ((v.y & 255) << 8) | ((v.z & 255) << 16) | ((v.w & 255) << 24);
    }
}

// ---------------- int8 GEMM, 4-phase split schedule (T3+T4+T5) ----------------
// BM=128, BN=256, BK=128B. 8 waves (WARPS_M=2 x WARPS_N=4), wave tile 64x64
// = 4x4 frags of 16x16x64 x 2 k-steps -> 32 MFMA/K-tile, 4 phases of 8.
// Grid (M/128)*(N/256) = 768 = exactly 3 blocks/CU (balanced).
// LDS: 3 buffers x (A 16KB + B 32KB) = 144KB, prefetch distance 2.
// Rows are 128B; fragment reads swizzled c ^= (r&7)<<4 (2 lanes/slot = free);
// staging = linear LDS dest via global_load_lds + inverse-swizzled global src
// (both-sides-or-neither, rule #21; involution verified conflict-free in R2).
// vmcnt ledger: 6 loads/K-tile/wave. Prologue stages T0,T1 (12 out). Boundary
// of iter kt: vmcnt(6) -> oldest 6 (= tile kt, issued 2 iters ago) retired,
// tile kt+1's 6 stay in flight; barrier publishes. Stage tile kt+2 during
// phases 0-2 (2 issues each). Last boundary vmcnt(0).
__global__ __launch_bounds__(512) void gemm_i8(
    const int8_t* __restrict__ xq, const int8_t* __restrict__ w,
    const float* __restrict__ sx, const float* __restrict__ scale,
    const float* __restrict__ bias, float* __restrict__ out,
    int M, int N, int K)
{
    __shared__ __align__(16) uint8_t lds[3][49152];
    const int tid  = threadIdx.x;
    const int lane = tid & 63;
    const int wv   = tid >> 6;
    const int wr   = wv >> 2, wc = wv & 3;

    // bijective XCD swizzle (m204); nwg=768 -> %8==0
    const int nwg = gridDim.x;
    const int q8 = nwg >> 3, r8 = nwg & 7;
    const int xcd = blockIdx.x & 7, idx8 = blockIdx.x >> 3;
    const int wg = (xcd < r8 ? xcd * (q8 + 1) : r8 * (q8 + 1) + (xcd - r8) * q8) + idx8;

    const int NBM = M >> 7;
    const int bm = wg % NBM;
    const int bn = wg / NBM;       // col-panel-major: B panel (1MB) L2-resident
    const int brow = bm << 7, bcol = bn << 8;

    // staging sources (inverse-swizzled): LDS chunk li covers bytes li*16..+15
    // of its region; physical row R=li>>3 (128B rows), in-row x=(li&7)<<4,
    // logical k-col = x ^ ((R&7)<<4).
    const int8_t* srcA[2];
    const int8_t* srcB[4];
    #pragma unroll
    for (int e = 0; e < 2; ++e) {
        int li = e * 512 + tid;
        int R  = li >> 3;
        int c  = ((li & 7) << 4) ^ ((R & 7) << 4);
        srcA[e] = xq + (size_t)(brow + R) * K + c;
    }
    #pragma unroll
    for (int e = 0; e < 4; ++e) {
        int li = e * 512 + tid;
        int R  = li >> 3;
        int c  = ((li & 7) << 4) ^ ((R & 7) << 4);
        srcB[e] = w + (size_t)(bcol + R) * K + c;
    }
    const int dstA = wv * 1024;            // wave-uniform base; HW adds lane*16
    const int dstB = 16384 + wv * 1024;

    // fragment LDS byte offsets (ks=0; ks=1 = ^64, valid under the XOR swizzle)
    int offA[4], offB[4];
    #pragma unroll
    for (int m = 0; m < 4; ++m) {
        int ra = wr * 64 + m * 16 + (lane & 15);
        offA[m] = ra * 128 + ((lane & 48) ^ ((ra & 7) << 4));
        int rb = wc * 64 + m * 16 + (lane & 15);
        offB[m] = 16384 + rb * 128 + ((lane & 48) ^ ((rb & 7) << 4));
    }

    i32x4 acc[4][4] = {};

    auto stageA = [&](int buf, int kt) {
        const size_t ko = (size_t)kt << 7;
        gload16(srcA[0] + ko, &lds[buf][dstA]);
        gload16(srcA[1] + ko, &lds[buf][8192 + dstA]);
    };
    auto stageB01 = [&](int buf, int kt) {
        const size_t ko = (size_t)kt << 7;
        gload16(srcB[0] + ko, &lds[buf][dstB]);
        gload16(srcB[1] + ko, &lds[buf][8192 + dstB]);
    };
    auto stageB23 = [&](int buf, int kt) {
        const size_t ko = (size_t)kt << 7;
        gload16(srcB[2] + ko, &lds[buf][16384 + dstB]);
        gload16(srcB[3] + ko, &lds[buf][24576 + dstB]);
    };

    const int NT = K >> 7;     // 32
    stageA(0, 0); stageB01(0, 0); stageB23(0, 0);
    if (NT > 1) { stageA(1, 1); stageB01(1, 1); stageB23(1, 1); }
    int cur = 0;
    for (int kt = 0; kt < NT; ++kt) {
        if (kt < NT - 1) { VMCNT(6); } else { VMCNT(0); }
        BARRIER();                               // tile kt visible to all waves
        const uint8_t* buf = lds[cur];
        const bool pf = (kt + 2 < NT);
        int nb = cur + 2; if (nb >= 3) nb -= 3;  // buf[(kt+2)%3]: reads done iter kt-1

        i32x4 av[2][2], bv[4][2];
        // ---- phase 0: read av(mh=0)+bv[0..1], stage A(kt+2), MFMA q(0,0) ----
        #pragma unroll
        for (int i = 0; i < 2; ++i) {
            av[i][0] = *(const i32x4*)(buf + offA[i]);
            av[i][1] = *(const i32x4*)(buf + (offA[i] ^ 64));
        }
        #pragma unroll
        for (int n = 0; n < 2; ++n) {
            bv[n][0] = *(const i32x4*)(buf + offB[n]);
            bv[n][1] = *(const i32x4*)(buf + (offB[n] ^ 64));
        }
        if (pf) stageA(nb, kt + 2);
        BARRIER();
        __builtin_amdgcn_s_setprio(1);
        #pragma unroll
        for (int i = 0; i < 2; ++i)
            #pragma unroll
            for (int n = 0; n < 2; ++n) {
                acc[i][n] = __builtin_amdgcn_mfma_i32_16x16x64_i8(av[i][0], bv[n][0], acc[i][n], 0, 0, 0);
                acc[i][n] = __builtin_amdgcn_mfma_i32_16x16x64_i8(av[i][1], bv[n][1], acc[i][n], 0, 0, 0);
            }
        __builtin_amdgcn_s_setprio(0);
        BARRIER();
        // ---- phase 1: read bv[2..3], stage B01(kt+2), MFMA q(0,1) ----
        #pragma unroll
        for (int n = 2; n < 4; ++n) {
            bv[n][0] = *(const i32x4*)(buf + offB[n]);
            bv[n][1] = *(const i32x4*)(buf + (offB[n] ^ 64));
        }
        if (pf) stageB01(nb, kt + 2);
        BARRIER();
        __builtin_amdgcn_s_setprio(1);
        #pragma unroll
        for (int i = 0; i < 2; ++i)
            #pragma unroll
            for (int n = 2; n < 4; ++n) {
                acc[i][n] = __builtin_amdgcn_mfma_i32_16x16x64_i8(av[i][0], bv[n][0], acc[i][n], 0, 0, 0);
                acc[i][n] = __builtin_amdgcn_mfma_i32_16x16x64_i8(av[i][1], bv[n][1], acc[i][n], 0, 0, 0);
            }
        __builtin_amdgcn_s_setprio(0);
        BARRIER();
        // ---- phase 2: read av(mh=1), stage B23(kt+2), MFMA q(1,0) ----
        #pragma unroll
        for (int i = 0; i < 2; ++i) {
            av[i][0] = *(const i32x4*)(buf + offA[2 + i]);
            av[i][1] = *(const i32x4*)(buf + (offA[2 + i] ^ 64));
        }
        if (pf) stageB23(nb, kt + 2);
        BARRIER();
        __builtin_amdgcn_s_setprio(1);
        #pragma unroll
        for (int i = 0; i < 2; ++i)
            #pragma unroll
            for (int n = 0; n < 2; ++n) {
                acc[2 + i][n] = __builtin_amdgcn_mfma_i32_16x16x64_i8(av[i][0], bv[n][0], acc[2 + i][n], 0, 0, 0);
                acc[2 + i][n] = __builtin_amdgcn_mfma_i32_16x16x64_i8(av[i][1], bv[n][1], acc[2 + i][n], 0, 0, 0);
            }
        __builtin_amdgcn_s_setprio(0);
        BARRIER();
        // ---- phase 3: MFMA q(1,1) (no reads/stages) ----
        __builtin_amdgcn_s_setprio(1);
        #pragma unroll
        for (int i = 0; i < 2; ++i)
            #pragma unroll
            for (int n = 2; n < 4; ++n) {
                acc[2 + i][n] = __builtin_amdgcn_mfma_i32_16x16x64_i8(av[i][0], bv[n][0], acc[2 + i][n], 0, 0, 0);
                acc[2 + i][n] = __builtin_amdgcn_mfma_i32_16x16x64_i8(av[i][1], bv[n][1], acc[2 + i][n], 0, 0, 0);
            }
        __builtin_amdgcn_s_setprio(0);
        if (++cur >= 3) cur = 0;
    }

    // epilogue: out = acc * sx[row] * scale[col] + bias[col]
    const int orow = brow + wr * 64;
    const int ocol = bcol + wc * 64;
    float sxv[4][4];
    #pragma unroll
    for (int m = 0; m < 4; ++m)
        #pragma unroll
        for (int j = 0; j < 4; ++j)
            sxv[m][j] = sx[orow + m * 16 + ((lane >> 4) << 2) + j];
    #pragma unroll
    for (int n = 0; n < 4; ++n) {
        const int col = ocol + n * 16 + (lane & 15);
        const float sc = scale[col];
        const float bi = bias[col];
        #pragma unroll
        for (int m = 0; m < 4; ++m) {
            const int rb = orow + m * 16 + ((lane >> 4) << 2);
            #pragma unroll
            for (int j = 0; j < 4; ++j)
                out[(size_t)(rb + j) * N + col] = (float)acc[m][n][j] * sxv[m][j] * sc + bi;
        }
    }
}

extern "C" void kernel_launch(void* const* d_in, const int* in_sizes, int n_in,
                              void* d_out, int out_size, void* d_ws, size_t ws_size,
                              hipStream_t stream) {
    const float* x     = (const float*)d_in[0];
    const int*   w32   = (const int*)d_in[1];     // int8 weight arrives as int32 (harness ABI)
    const float* scale = (const float*)d_in[2];
    const float* bias  = (const float*)d_in[3];
    float* out = (float*)d_out;

    const int N = in_sizes[2];           // 6144
    const int K = in_sizes[1] / N;       // 4096
    const int M = in_sizes[0] / K;       // 4096

    // ws layout: xq [M*K int8] | wq [N*K int8] | sx [M f32]
    int8_t* xqbuf = (int8_t*)d_ws;
    int8_t* wqbuf = (int8_t*)d_ws + (size_t)M * K;
    float*  sxbuf = (float*)((uint8_t*)d_ws + (size_t)M * K + (size_t)N * K);

    if (K == 4096)
        quant4096<<<M, 256, 0, stream>>>(x, xqbuf, sxbuf);
    else
        quant_any<<<M, 256, 0, stream>>>(x, xqbuf, sxbuf, K);

    pack_w<<<2048, 256, 0, stream>>>(w32, wqbuf, (long long)N * K / 4);

    const int nwg = (M / 128) * (N / 256);   // 32*24 = 768
    gemm_i8<<<nwg, 512, 0, stream>>>(xqbuf, wqbuf, sxbuf, scale, bias, out, M, N, K);
}